// Round 12
// baseline (24.550 us; speedup 1.0000x reference)
//
#include <hip/hip_runtime.h>
#include <math.h>

// Problem constants (from setup_inputs): xcorr [32, 3, 64, 4096] fp32, nlag = 2048.
#define NB 32
#define NC 3
#define NX 64
#define NT 4096

struct Quad { float4 a, b, c, d; };

// Load 16 consecutive floats for this lane within a 1024-elem chunk:
// base = chunk*1024 + lane*16 (64B-aligned), 4 aligned dwordx4.
__device__ __forceinline__ Quad load_chunk16(const float* __restrict__ xr,
                                             int coff, int lane) {
    const float* base = xr + (size_t)coff + (size_t)(lane << 4);
    Quad q;
    q.a = *reinterpret_cast<const float4*>(base);
    q.b = *reinterpret_cast<const float4*>(base + 4);
    q.c = *reinterpret_cast<const float4*>(base + 8);
    q.d = *reinterpret_cast<const float4*>(base + 12);
    return q;
}

// keep = (x == 3-tap max) <=> (x >= l && x >= r); candidate = x*keep
// (zeros stay candidates, like the reference's x*keep array).
__device__ __forceinline__ float keep3(float l, float x, float r) {
    const float m = fmaxf(fmaxf(l, x), r);   // v_max3_f32
    return (x == m) ? x : 0.0f;
}

// Branch-free top-2 insert (ascending index order). m1 is value-only.
// Strict > keeps the lowest index on ties (lax.top_k); equal-to-max
// duplicates land in m1 via max (s1 == s0).
__device__ __forceinline__ void ins(float c, int t, float& m0, int& i0, float& m1) {
    const bool g = c > m0;
    m1 = g ? m0 : fmaxf(m1, c);
    m0 = fmaxf(m0, c);
    i0 = g ? t : i0;
}

// Scan one 1024-elem chunk held in q (lane covers 16 consecutive elems).
// lmE = |prev chunk's last elem| (or -INF at row start); rmE = |next chunk's
// first elem| (or -INF at row end); both lane-uniform, used by lane 0/63.
// Only 2 shuffles here; all interior neighbors are register-local.
__device__ __forceinline__ void scan_chunk16(Quad q, float lmE, float rmE,
                                             int coff, int lane,
                                             float& m0, int& i0, float& m1)
{
    const int tb = coff + (lane << 4);

    const float e0  = fabsf(q.a.x), e1  = fabsf(q.a.y), e2  = fabsf(q.a.z), e3  = fabsf(q.a.w);
    const float e4  = fabsf(q.b.x), e5  = fabsf(q.b.y), e6  = fabsf(q.b.z), e7  = fabsf(q.b.w);
    const float e8  = fabsf(q.c.x), e9  = fabsf(q.c.y), e10 = fabsf(q.c.z), e11 = fabsf(q.c.w);
    const float e12 = fabsf(q.d.x), e13 = fabsf(q.d.y), e14 = fabsf(q.d.z), e15 = fabsf(q.d.w);

    float lm = __shfl_up(e15, 1);
    lm = (lane == 0) ? lmE : lm;
    float rm = __shfl_down(e0, 1);
    rm = (lane == 63) ? rmE : rm;

    ins(keep3(lm,  e0,  e1 ), tb + 0,  m0, i0, m1);
    ins(keep3(e0,  e1,  e2 ), tb + 1,  m0, i0, m1);
    ins(keep3(e1,  e2,  e3 ), tb + 2,  m0, i0, m1);
    ins(keep3(e2,  e3,  e4 ), tb + 3,  m0, i0, m1);
    ins(keep3(e3,  e4,  e5 ), tb + 4,  m0, i0, m1);
    ins(keep3(e4,  e5,  e6 ), tb + 5,  m0, i0, m1);
    ins(keep3(e5,  e6,  e7 ), tb + 6,  m0, i0, m1);
    ins(keep3(e6,  e7,  e8 ), tb + 7,  m0, i0, m1);
    ins(keep3(e7,  e8,  e9 ), tb + 8,  m0, i0, m1);
    ins(keep3(e8,  e9,  e10), tb + 9,  m0, i0, m1);
    ins(keep3(e9,  e10, e11), tb + 10, m0, i0, m1);
    ins(keep3(e10, e11, e12), tb + 11, m0, i0, m1);
    ins(keep3(e11, e12, e13), tb + 12, m0, i0, m1);
    ins(keep3(e12, e13, e14), tb + 13, m0, i0, m1);
    ins(keep3(e13, e14, e15), tb + 14, m0, i0, m1);
    ins(keep3(e14, e15, rm ), tb + 15, m0, i0, m1);
}

// Lexicographic merge of two chunk accumulators where ALL of b's indices are
// greater than a's (ascending chunk order) — tie keeps a.
__device__ __forceinline__ void merge_acc(float& m0, int& i0, float& m1,
                                          float bm0, int bi0, float bm1)
{
    const bool big = bm0 > m0;               // tie -> keep a (lower index)
    const float loser = big ? m0 : bm0;
    m1 = fmaxf(fmaxf(m1, bm1), loser);
    m0 = big ? bm0 : m0;
    i0 = big ? bi0 : i0;
}

// Single fused kernel: one block per (b,x) tile, 3 waves (192 threads), wave c
// scans channel-row c with the R10 lean scan. Each wave also prefetches its
// own top-1's clipped neighbors (uniform loads, issued pre-barrier, overlap
// sibling butterflies) so the post-barrier epilogue is load-free. One tiny
// LDS exchange + one barrier; wave 0 runs the verbatim epilogue math.
__global__ __launch_bounds__(192) void detect_peaks_kernel(
    const float* __restrict__ xcorr,
    const int*   __restrict__ nlag_p,
    float* __restrict__ out)
{
    __shared__ float sv0[NC], sv1[NC], snm[NC], snp[NC];
    __shared__ int   si0[NC];

    const int g    = blockIdx.x;            // tile index = b*NX + x
    const int b    = g >> 6;
    const int x    = g & 63;
    const int tid  = threadIdx.x;
    const int lane = tid & 63;
    const int wid  = tid >> 6;              // channel 0..2

    const int row = (b * NC + wid) * NX + x;
    const float* __restrict__ xr = xcorr + (size_t)row * NT;

    // ---- R10 lean wave scan of this row ----
    float m0a = -1.0f, m1a = -1.0f; int i0a = 0;
    float m0b = -1.0f, m1b = -1.0f; int i0b = 0;
    float m0c = -1.0f, m1c = -1.0f; int i0c = 0;
    float m0d = -1.0f, m1d = -1.0f; int i0d = 0;

    Quad q0 = load_chunk16(xr, 0,    lane);
    Quad q1 = load_chunk16(xr, 1024, lane);

    // chunk 0 (row start: -INF pad, matching reduce_window)
    Quad q2 = load_chunk16(xr, 2048, lane);
    float nf = __shfl(fabsf(q1.a.x), 0);
    scan_chunk16(q0, -INFINITY, nf, 0, lane, m0a, i0a, m1a);
    float pl = __shfl(fabsf(q0.d.w), 63);

    // chunk 1
    Quad q3 = load_chunk16(xr, 3072, lane);
    nf = __shfl(fabsf(q2.a.x), 0);
    scan_chunk16(q1, pl, nf, 1024, lane, m0b, i0b, m1b);
    pl = __shfl(fabsf(q1.d.w), 63);

    // chunk 2
    nf = __shfl(fabsf(q3.a.x), 0);
    scan_chunk16(q2, pl, nf, 2048, lane, m0c, i0c, m1c);
    pl = __shfl(fabsf(q2.d.w), 63);

    // chunk 3 (row end: -INF pad)
    scan_chunk16(q3, pl, -INFINITY, 3072, lane, m0d, i0d, m1d);

    // in-lane merge, ascending chunk (=index) order
    merge_acc(m0a, i0a, m1a, m0b, i0b, m1b);
    merge_acc(m0c, i0c, m1c, m0d, i0d, m1d);
    merge_acc(m0a, i0a, m1a, m0c, i0c, m1c);
    float v0 = m0a, v1 = m1a; int i0 = i0a;

    // wave butterfly top-2 merge (lexicographic on (value desc, index asc))
    #pragma unroll
    for (int off = 1; off < 64; off <<= 1) {
        const float ov0 = __shfl_xor(v0, off);
        const int   oi0 = __shfl_xor(i0, off);
        const float ov1 = __shfl_xor(v1, off);
        const bool big = (ov0 > v0) || (ov0 == v0 && oi0 < i0);
        const float loser = big ? v0 : ov0;
        v1 = fmaxf(fmaxf(v1, ov1), loser);
        v0 = big ? ov0 : v0;
        i0 = big ? oi0 : i0;
    }

    // prefetch this row's clipped top-1 neighbors (i0 is wave-uniform now);
    // same clipping math the epilogue would use if this channel is selected
    if (lane == 0) {
        const float ym1 = fabsf(xr[i0 > 0 ? i0 - 1 : 0]);
        const float yp1 = fabsf(xr[i0 < NT - 1 ? i0 + 1 : NT - 1]);
        sv0[wid] = v0; si0[wid] = i0; sv1[wid] = v1;
        snm[wid] = ym1; snp[wid] = yp1;
    }
    __syncthreads();   // the only barrier

    // ---- wave 0: load-free epilogue (verbatim R8/R11 math) ----
    if (wid == 0) {
        const float m00 = sv0[0], m10 = sv1[0]; const int p0 = si0[0];
        const float m01 = sv0[1], m11 = sv1[1]; const int p1 = si0[1];
        const float m02 = sv0[2], m12 = sv1[2]; const int p2 = si0[2];

        const float w0 = (0.1f + 3.0f * (m00 - m10)) * (m00 * m00);
        const float w1 = (0.1f + 3.0f * (m01 - m11)) * (m01 * m01);
        const float w2 = (0.1f + 3.0f * (m02 - m12)) * (m02 * m02);

        // channel argmax, first occurrence (ascending c, strict >) — branch-free
        const bool t1 = w1 > w0;
        float bw = t1 ? w1 : w0;
        float bs = t1 ? m01 : m00;
        int   bp = t1 ? p1 : p0;
        int   cs = t1 ? 1 : 0;
        const bool t2 = w2 > bw;
        bw = t2 ? w2 : bw;
        bs = t2 ? m02 : bs;
        bp = t2 ? p2 : bp;
        cs = t2 ? 2 : cs;

        // parabola through clipped neighbors (prefetched by the selected wave)
        const float ym1 = snm[cs];
        const float yp1 = snp[cs];
        const float A = 0.5f * (ym1 + yp1) - bs;   // <= 0 up to FP rounding
        const float B = 0.5f * (yp1 - ym1);
        const float C = bs;

        // closed-form grid argmax of yg=(A*xg+B)*xg+C over xg=linspace(-1,1,201):
        // evaluate the 4 grid points bracketing the vertex with the SAME FP
        // formula as the reference; first-max tie-break (ascending candidates).
        int gi; float bv;
        if (A == 0.0f) {
            gi = (B > 0.0f) ? 200 : 0;
            const float xg = 0.01f * (float)(gi - 100);
            bv = (A * xg + B) * xg + C;
        } else {
            float gv = (1.0f - 0.5f * B / A) * 100.0f;  // vertex in grid coords
            gv = fminf(fmaxf(gv, 0.0f), 200.0f);
            const int glo = (int)gv;
            bv = -INFINITY; gi = 0;
            #pragma unroll
            for (int d = -1; d <= 2; ++d) {
                int gg = glo + d;
                gg = gg < 0 ? 0 : (gg > 200 ? 200 : gg);
                const float xg = 0.01f * (float)(gg - 100);
                const float yg = (A * xg + B) * xg + C;
                if (yg > bv) { bv = yg; gi = gg; }      // strict > = first occurrence
            }
        }

        if (lane == 0) {
            const float fidx = (float)bp + 0.01f * (float)(gi - 100);
            const float nlagf = (float)(*nlag_p);
            const float shift_idx = fidx - nlagf;
            const int n = NB * NX;
            out[0 * n + g] = bv;                  // max_cc (interpolated score)
            out[1 * n + g] = bw;                  // weight
            out[2 * n + g] = shift_idx / 100.0f;  // shift_t (SAMPLING_RATE = 100)
            out[3 * n + g] = shift_idx;           // shift_idx
        }
    }
}

extern "C" void kernel_launch(void* const* d_in, const int* in_sizes, int n_in,
                              void* d_out, int out_size, void* d_ws, size_t ws_size,
                              hipStream_t stream) {
    const float* xcorr  = (const float*)d_in[0];
    const int*   nlag_p = (const int*)d_in[1];
    float* out = (float*)d_out;

    detect_peaks_kernel<<<NB * NX, 192, 0, stream>>>(xcorr, nlag_p, out);
}

// Round 13
// 23.836 us; speedup vs baseline: 1.0299x; 1.0299x over previous
//
#include <hip/hip_runtime.h>
#include <math.h>

// Problem constants (from setup_inputs): xcorr [32, 3, 64, 4096] fp32, nlag = 2048.
#define NB 32
#define NC 3
#define NX 64
#define NT 4096

struct Quad { float4 a, b, c, d; };

// Load 16 consecutive floats for this lane within a 1024-elem chunk:
// base = chunk*1024 + lane*16 (64B-aligned), 4 aligned dwordx4.
__device__ __forceinline__ Quad load_chunk16(const float* __restrict__ xr,
                                             int coff, int lane) {
    const float* base = xr + (size_t)coff + (size_t)(lane << 4);
    Quad q;
    q.a = *reinterpret_cast<const float4*>(base);
    q.b = *reinterpret_cast<const float4*>(base + 4);
    q.c = *reinterpret_cast<const float4*>(base + 8);
    q.d = *reinterpret_cast<const float4*>(base + 12);
    return q;
}

// keep = (x == 3-tap max) <=> (x >= l && x >= r); candidate = x*keep
// (zeros stay candidates, like the reference's x*keep array).
__device__ __forceinline__ float keep3(float l, float x, float r) {
    const float m = fmaxf(fmaxf(l, x), r);   // v_max3_f32
    return (x == m) ? x : 0.0f;
}

// Branch-free top-2 insert (ascending index order). m1 is value-only.
// Strict > keeps the lowest index on ties (lax.top_k); equal-to-max
// duplicates land in m1 via max (s1 == s0).
__device__ __forceinline__ void ins(float c, int t, float& m0, int& i0, float& m1) {
    const bool g = c > m0;
    m1 = g ? m0 : fmaxf(m1, c);
    m0 = fmaxf(m0, c);
    i0 = g ? t : i0;
}

// Scan one 1024-elem chunk held in q (lane covers 16 consecutive elems).
// lmE = |prev chunk's last elem| (or -INF at row start); rmE = |next chunk's
// first elem| (or -INF at row end); both lane-uniform, used by lane 0/63.
// Only 2 shuffles here; all interior neighbors are register-local.
__device__ __forceinline__ void scan_chunk16(Quad q, float lmE, float rmE,
                                             int coff, int lane,
                                             float& m0, int& i0, float& m1)
{
    const int tb = coff + (lane << 4);

    const float e0  = fabsf(q.a.x), e1  = fabsf(q.a.y), e2  = fabsf(q.a.z), e3  = fabsf(q.a.w);
    const float e4  = fabsf(q.b.x), e5  = fabsf(q.b.y), e6  = fabsf(q.b.z), e7  = fabsf(q.b.w);
    const float e8  = fabsf(q.c.x), e9  = fabsf(q.c.y), e10 = fabsf(q.c.z), e11 = fabsf(q.c.w);
    const float e12 = fabsf(q.d.x), e13 = fabsf(q.d.y), e14 = fabsf(q.d.z), e15 = fabsf(q.d.w);

    float lm = __shfl_up(e15, 1);
    lm = (lane == 0) ? lmE : lm;
    float rm = __shfl_down(e0, 1);
    rm = (lane == 63) ? rmE : rm;

    ins(keep3(lm,  e0,  e1 ), tb + 0,  m0, i0, m1);
    ins(keep3(e0,  e1,  e2 ), tb + 1,  m0, i0, m1);
    ins(keep3(e1,  e2,  e3 ), tb + 2,  m0, i0, m1);
    ins(keep3(e2,  e3,  e4 ), tb + 3,  m0, i0, m1);
    ins(keep3(e3,  e4,  e5 ), tb + 4,  m0, i0, m1);
    ins(keep3(e4,  e5,  e6 ), tb + 5,  m0, i0, m1);
    ins(keep3(e5,  e6,  e7 ), tb + 6,  m0, i0, m1);
    ins(keep3(e6,  e7,  e8 ), tb + 7,  m0, i0, m1);
    ins(keep3(e7,  e8,  e9 ), tb + 8,  m0, i0, m1);
    ins(keep3(e8,  e9,  e10), tb + 9,  m0, i0, m1);
    ins(keep3(e9,  e10, e11), tb + 10, m0, i0, m1);
    ins(keep3(e10, e11, e12), tb + 11, m0, i0, m1);
    ins(keep3(e11, e12, e13), tb + 12, m0, i0, m1);
    ins(keep3(e12, e13, e14), tb + 13, m0, i0, m1);
    ins(keep3(e13, e14, e15), tb + 14, m0, i0, m1);
    ins(keep3(e14, e15, rm ), tb + 15, m0, i0, m1);
}

// Lexicographic merge of two chunk accumulators where ALL of b's indices are
// greater than a's (ascending chunk order) — tie keeps a.
__device__ __forceinline__ void merge_acc(float& m0, int& i0, float& m1,
                                          float bm0, int bi0, float bm1)
{
    const bool big = bm0 > m0;               // tie -> keep a (lower index)
    const float loser = big ? m0 : bm0;
    m1 = fmaxf(fmaxf(m1, bm1), loser);
    m0 = big ? bm0 : m0;
    i0 = big ? bi0 : i0;
}

// Single fused kernel: one block per (b,x) tile, 3 waves (192 threads), wave c
// scans channel-row c with the R10 lean scan (no edge loads, 4 DS ops/chunk,
// per-chunk accumulators). One tiny LDS exchange + one barrier; wave 0 runs
// the verbatim R8 epilogue and writes the 4 stacked outputs. No workspace.
__global__ __launch_bounds__(192) void detect_peaks_kernel(
    const float* __restrict__ xcorr,
    const int*   __restrict__ nlag_p,
    float* __restrict__ out)
{
    __shared__ float sv0[NC], sv1[NC];
    __shared__ int   si0[NC];

    const int g    = blockIdx.x;            // tile index = b*NX + x
    const int b    = g >> 6;
    const int x    = g & 63;
    const int tid  = threadIdx.x;
    const int lane = tid & 63;
    const int wid  = tid >> 6;              // channel 0..2

    const int row = (b * NC + wid) * NX + x;
    const float* __restrict__ xr = xcorr + (size_t)row * NT;

    // ---- R10 lean wave scan of this row ----
    float m0a = -1.0f, m1a = -1.0f; int i0a = 0;
    float m0b = -1.0f, m1b = -1.0f; int i0b = 0;
    float m0c = -1.0f, m1c = -1.0f; int i0c = 0;
    float m0d = -1.0f, m1d = -1.0f; int i0d = 0;

    Quad q0 = load_chunk16(xr, 0,    lane);
    Quad q1 = load_chunk16(xr, 1024, lane);

    // chunk 0 (row start: -INF pad, matching reduce_window)
    Quad q2 = load_chunk16(xr, 2048, lane);
    float nf = __shfl(fabsf(q1.a.x), 0);
    scan_chunk16(q0, -INFINITY, nf, 0, lane, m0a, i0a, m1a);
    float pl = __shfl(fabsf(q0.d.w), 63);

    // chunk 1
    Quad q3 = load_chunk16(xr, 3072, lane);
    nf = __shfl(fabsf(q2.a.x), 0);
    scan_chunk16(q1, pl, nf, 1024, lane, m0b, i0b, m1b);
    pl = __shfl(fabsf(q1.d.w), 63);

    // chunk 2
    nf = __shfl(fabsf(q3.a.x), 0);
    scan_chunk16(q2, pl, nf, 2048, lane, m0c, i0c, m1c);
    pl = __shfl(fabsf(q2.d.w), 63);

    // chunk 3 (row end: -INF pad)
    scan_chunk16(q3, pl, -INFINITY, 3072, lane, m0d, i0d, m1d);

    // in-lane merge, ascending chunk (=index) order
    merge_acc(m0a, i0a, m1a, m0b, i0b, m1b);
    merge_acc(m0c, i0c, m1c, m0d, i0d, m1d);
    merge_acc(m0a, i0a, m1a, m0c, i0c, m1c);
    float v0 = m0a, v1 = m1a; int i0 = i0a;

    // wave butterfly top-2 merge (lexicographic on (value desc, index asc))
    #pragma unroll
    for (int off = 1; off < 64; off <<= 1) {
        const float ov0 = __shfl_xor(v0, off);
        const int   oi0 = __shfl_xor(i0, off);
        const float ov1 = __shfl_xor(v1, off);
        const bool big = (ov0 > v0) || (ov0 == v0 && oi0 < i0);
        const float loser = big ? v0 : ov0;
        v1 = fmaxf(fmaxf(v1, ov1), loser);
        v0 = big ? ov0 : v0;
        i0 = big ? oi0 : i0;
    }

    if (lane == 0) { sv0[wid] = v0; si0[wid] = i0; sv1[wid] = v1; }
    __syncthreads();   // the only barrier

    // ---- wave 0: verbatim R8 epilogue (uniform across its 64 lanes) ----
    if (wid == 0) {
        const float m00 = sv0[0], m10 = sv1[0]; const int p0 = si0[0];
        const float m01 = sv0[1], m11 = sv1[1]; const int p1 = si0[1];
        const float m02 = sv0[2], m12 = sv1[2]; const int p2 = si0[2];

        const float w0 = (0.1f + 3.0f * (m00 - m10)) * (m00 * m00);
        const float w1 = (0.1f + 3.0f * (m01 - m11)) * (m01 * m01);
        const float w2 = (0.1f + 3.0f * (m02 - m12)) * (m02 * m02);

        // channel argmax, first occurrence (ascending c, strict >) — branch-free
        const bool t1 = w1 > w0;
        float bw = t1 ? w1 : w0;
        float bs = t1 ? m01 : m00;
        int   bp = t1 ? p1 : p0;
        int   cs = t1 ? 1 : 0;
        const bool t2 = w2 > bw;
        bw = t2 ? w2 : bw;
        bs = t2 ? m02 : bs;
        bp = t2 ? p2 : bp;
        cs = t2 ? 2 : cs;

        const float* __restrict__ xrs = xcorr + (size_t)((b * NC + cs) * NX + x) * NT;

        // parabola through clipped neighbors of the selected peak (L1-hot:
        // this row was just streamed by a sibling wave on this CU)
        const float ym1 = fabsf(xrs[bp > 0 ? bp - 1 : 0]);
        const float yp1 = fabsf(xrs[bp < NT - 1 ? bp + 1 : NT - 1]);
        const float A = 0.5f * (ym1 + yp1) - bs;   // <= 0 up to FP rounding
        const float B = 0.5f * (yp1 - ym1);
        const float C = bs;

        // closed-form grid argmax of yg=(A*xg+B)*xg+C over xg=linspace(-1,1,201):
        // evaluate the 4 grid points bracketing the vertex with the SAME FP
        // formula as the reference; first-max tie-break (ascending candidates).
        int gi; float bv;
        if (A == 0.0f) {
            gi = (B > 0.0f) ? 200 : 0;
            const float xg = 0.01f * (float)(gi - 100);
            bv = (A * xg + B) * xg + C;
        } else {
            float gv = (1.0f - 0.5f * B / A) * 100.0f;  // vertex in grid coords
            gv = fminf(fmaxf(gv, 0.0f), 200.0f);
            const int glo = (int)gv;
            bv = -INFINITY; gi = 0;
            #pragma unroll
            for (int d = -1; d <= 2; ++d) {
                int gg = glo + d;
                gg = gg < 0 ? 0 : (gg > 200 ? 200 : gg);
                const float xg = 0.01f * (float)(gg - 100);
                const float yg = (A * xg + B) * xg + C;
                if (yg > bv) { bv = yg; gi = gg; }      // strict > = first occurrence
            }
        }

        if (lane == 0) {
            const float fidx = (float)bp + 0.01f * (float)(gi - 100);
            const float nlagf = (float)(*nlag_p);
            const float shift_idx = fidx - nlagf;
            const int n = NB * NX;
            out[0 * n + g] = bv;                  // max_cc (interpolated score)
            out[1 * n + g] = bw;                  // weight
            out[2 * n + g] = shift_idx / 100.0f;  // shift_t (SAMPLING_RATE = 100)
            out[3 * n + g] = shift_idx;           // shift_idx
        }
    }
}

extern "C" void kernel_launch(void* const* d_in, const int* in_sizes, int n_in,
                              void* d_out, int out_size, void* d_ws, size_t ws_size,
                              hipStream_t stream) {
    const float* xcorr  = (const float*)d_in[0];
    const int*   nlag_p = (const int*)d_in[1];
    float* out = (float*)d_out;

    detect_peaks_kernel<<<NB * NX, 192, 0, stream>>>(xcorr, nlag_p, out);
}